// Round 8
// baseline (277.461 us; speedup 1.0000x reference)
//
#include <hip/hip_runtime.h>
#include <math.h>

// ---------------------------------------------------------------------------
// Round 8: dispatch-count collapse (12 -> 5).
//  - conv_all: conv1+conv2+conv3 fully fused, 1 block = 1 batch, all
//    intermediates in LDS (77,952 B static: s_out1 46.1KB + 30.7KB union of
//    {bf16 twin-padded image, conv2 padded output}). Index math identical to
//    the proven R6/R7 kernels; only destinations changed.
//  - fcn_k: fc1+fc2+fc3+norm fused (32 blocks x 16 rows, z1/z2/z3 in LDS).
//  - repack_k also zeroes the max slot (no memset dispatch).
// ---------------------------------------------------------------------------

#define BN_EPS 1e-5f

typedef __attribute__((ext_vector_type(8))) short short8;   // 8 bf16 = 4 VGPR
typedef __attribute__((ext_vector_type(4))) float f32x4;

__device__ __forceinline__ unsigned short f2bf(float f) {
    unsigned u = __float_as_uint(f);
    u += 0x7fffu + ((u >> 16) & 1u);          // round-to-nearest-even
    return (unsigned short)(u >> 16);
}

// ---- weight repack + fc-weight bf16 cast + mx zero -------------------------
// wT1b[oc 16][k 32] bf16, k=ky*4+kx (<24), pad 0                   (512)
// wT2b[kk=ky*2+kxp][oc 32][k 32] bf16, k=hi*16+ic <-> kx=2*kxp+hi (12288)
// wT3b[kk=ky*4+kx ][oc 64][ic 32] bf16                            (49152)
__global__ __launch_bounds__(256) void repack_k(
    const float* __restrict__ w1, const float* __restrict__ w2,
    const float* __restrict__ w3,
    const float* __restrict__ fw1, const float* __restrict__ fw2,
    const float* __restrict__ fw3,
    unsigned short* __restrict__ wT1b,
    unsigned short* __restrict__ wT2b, unsigned short* __restrict__ wT3b,
    unsigned short* __restrict__ fw1b, unsigned short* __restrict__ fw2b,
    unsigned short* __restrict__ fw3b, unsigned* __restrict__ mxslot)
{
    int t = blockIdx.x * 256 + threadIdx.x;
    if (t == 0) *mxslot = 0u;
    if (t < 512) {
        int k = t & 31, oc = t >> 5;
        wT1b[t] = (k < 24) ? f2bf(w1[oc * 24 + k]) : (unsigned short)0;
    }
    if (t < 12288) {
        int k = t & 31, oc = (t >> 5) & 31, kk = t >> 10;
        int ky = kk >> 1, kxp = kk & 1;
        int hi = k >> 4, ic = k & 15;
        int kx = 2 * kxp + hi;
        wT2b[t] = f2bf(w2[((oc * 16 + ic) * 6 + ky) * 4 + kx]);
    }
    if (t < 49152) {
        int ic = t & 31, oc = (t >> 5) & 63, kk = t >> 11;
        int ky = kk >> 2, kx = kk & 3;
        wT3b[t] = f2bf(w3[((oc * 32 + ic) * 6 + ky) * 4 + kx]);
    }
    if (t < 786432) fw1b[t] = f2bf(fw1[t]);
    if (t < 131072) fw2b[t] = f2bf(fw2[t]);
    if (t < 32768)  fw3b[t] = f2bf(fw3[t]);
}

// ---- conv_all: full conv stack, 1 block = 1 batch --------------------------
// LDS: s_out1 = conv1 out, padded HWC bf16 [41][36][16] (46.1 KB)
//      s_un   = union { pa/pb bf16 twin-padded image [79][68]x2 (21.5 KB),
//                       conv2 out padded HWC bf16 [24][20][32] (30.7 KB) }
__global__ __launch_bounds__(512) void conv_all(
    const float* __restrict__ x, const unsigned short* __restrict__ wT1,
    const unsigned short* __restrict__ wT2, const unsigned short* __restrict__ wT3,
    const float* __restrict__ c1b, const float* __restrict__ g1,
    const float* __restrict__ b1, const float* __restrict__ m1,
    const float* __restrict__ v1,
    const float* __restrict__ c2b, const float* __restrict__ g2,
    const float* __restrict__ b2, const float* __restrict__ m2,
    const float* __restrict__ v2,
    const float* __restrict__ c3b, const float* __restrict__ g3,
    const float* __restrict__ b3, const float* __restrict__ m3,
    const float* __restrict__ v3,
    unsigned short* __restrict__ out3)
{
    __shared__ __align__(16) unsigned short s_out1[41 * 36 * 16];  // 47232 B
    __shared__ __align__(16) unsigned short s_un[24 * 20 * 32];    // 30720 B
    const int tid = threadIdx.x, nl = blockIdx.x;
    const int lane = tid & 63, wave = tid >> 6;
    const int n = lane & 15, q = lane >> 4;
    unsigned short* pa = s_un;           // [79][68]: pa[r][c] = img[r-2][c-1]
    unsigned short* pb = s_un + 5372;    // [79][68]: pb[r][c] = img[r-2][c-2]

    // ---- zero pa/pb fully + s_out1 pad cells ------------------------------
    {
        unsigned* z32 = (unsigned*)s_un;
        for (int i = tid; i < 5372; i += 512) z32[i] = 0u;
        uint4 z4; z4.x = z4.y = z4.z = z4.w = 0u;
        for (int pc = tid; pc < 324; pc += 512) {
            int row, colc;
            if (pc < 180) { row = pc / 36; colc = pc % 36; if (row >= 2) row += 36; }
            else { int pz = pc - 180; row = 2 + (pz >> 2); colc = (pz & 3) ? 32 + (pz & 3) : 0; }
            uint4* d = (uint4*)(s_out1 + ((size_t)row * 36 + colc) * 16);
            d[0] = z4; d[1] = z4;
        }
    }
    __syncthreads();
    // ---- stage image as bf16 twin copies ----------------------------------
    {
        const float4* src = (const float4*)(x + (size_t)nl * 4608);
        for (int i = tid; i < 1152; i += 512) {
            float4 val = src[i];
            int f = i * 4, row = (f >> 6) + 2, c = (f & 63) + 1;   // c odd
            unsigned short h0 = f2bf(val.x), h1 = f2bf(val.y);
            unsigned short h2 = f2bf(val.z), h3 = f2bf(val.w);
            unsigned short* ap = pa + row * 68 + c;
            ap[0] = h0; ap[1] = h1; ap[2] = h2; ap[3] = h3;
            unsigned* bp = (unsigned*)(pb + row * 68 + c + 1);     // even idx
            bp[0] = (unsigned)h0 | ((unsigned)h1 << 16);
            bp[1] = (unsigned)h2 | ((unsigned)h3 << 16);
        }
    }
    const float sc1 = g1[n] * rsqrtf(v1[n] + BN_EPS);
    const float bb1 = c1b[n];
    const float mm1 = b1[n] - m1[n] * sc1;
    const short8 bfr1 = *(const short8*)(wT1 + n * 32 + q * 8);
    __syncthreads();

    // ---- phase A: conv1 (8 waves x 36 tiles, M=pos pooled*4+quad) ---------
    for (int i = 0; i < 36; ++i) {
        int t = wave * 36 + i;
        int pooled = 4 * t + (n >> 2);
        int ph = pooled >> 5, pw = pooled & 31;
        int py = (n >> 1) & 1, px = n & 1;
        int oh = 2 * ph + py, ow = 2 * pw + px;
        int r0 = (oh + 2 * q) * 68;
        const unsigned* base = px ? (const unsigned*)(pb + r0 + ow + 1)
                                  : (const unsigned*)(pa + r0 + ow);
        uint4 uu;
        uu.x = base[0];  uu.y = base[1];      // row oh+2q,   taps kx0..3
        uu.z = base[34]; uu.w = base[35];     // row oh+2q+1, taps kx0..3
        short8 afr = *reinterpret_cast<short8*>(&uu);
        f32x4 acc = (f32x4){0.f, 0.f, 0.f, 0.f};
        acc = __builtin_amdgcn_mfma_f32_16x16x32_bf16(afr, bfr1, acc, 0, 0, 0);
        int po = 4 * t + q, oph = po >> 5, opw = po & 31;
        float mx = fmaxf(fmaxf(acc[0], acc[1]), fmaxf(acc[2], acc[3]));
        float val = fmaxf(mx + bb1, 0.f) * sc1 + mm1;
        s_out1[((oph + 2) * 36 + (opw + 1)) * 16 + n] = f2bf(val);
    }
    __syncthreads();
    // ---- zero conv2-out pad cells (overwrites pa/pb region — reads done) --
    {
        uint4 z4; z4.x = z4.y = z4.z = z4.w = 0u;
        for (int pc = tid; pc < 192; pc += 512) {
            int row, colc;
            if (pc < 120) { row = pc / 20; colc = pc % 20; if (row >= 2) row += 18; }
            else { int pz = pc - 120; row = 2 + (pz >> 2); colc = (pz & 3) ? 16 + (pz & 3) : 0; }
            uint4* d = (uint4*)(s_un + ((size_t)row * 20 + colc) * 32);
            d[0] = z4; d[1] = z4; d[2] = z4; d[3] = z4;
        }
    }
    float bnb2[2], bns2[2], bnm2[2];
#pragma unroll
    for (int nt = 0; nt < 2; ++nt) {
        int oc = nt * 16 + n;
        float sc = g2[oc] * rsqrtf(v2[oc] + BN_EPS);
        bnb2[nt] = c2b[oc]; bns2[nt] = sc; bnm2[nt] = b2[oc] - m2[oc] * sc;
    }
    __syncthreads();

    // ---- phase B: conv2 (pp loop over 36 pool-pair positions) -------------
    for (int pp = wave; pp < 36; pp += 8) {
        int ph = pp >> 1, half = pp & 1;
        f32x4 acc[2][2];                       // [row a/b][nt]
#pragma unroll
        for (int ab = 0; ab < 2; ++ab)
#pragma unroll
            for (int nt = 0; nt < 2; ++nt) acc[ab][nt] = (f32x4){0.f, 0.f, 0.f, 0.f};
#pragma unroll
        for (int ky = 0; ky < 6; ++ky)
#pragma unroll
            for (int kxp = 0; kxp < 2; ++kxp) {
                int kk = ky * 2 + kxp;
                short8 w0 = *(const short8*)(wT2 + ((size_t)(kk * 32 + n) * 32) + q * 8);
                short8 w1 = *(const short8*)(wT2 + ((size_t)(kk * 32 + 16 + n) * 32) + q * 8);
                int col = half * 16 + n + 2 * kxp;
#pragma unroll
                for (int ab = 0; ab < 2; ++ab) {
                    int row = 2 * ph + ab + ky;
                    short8 afr = *(const short8*)(s_out1 + ((size_t)(row * 36 + col) * 16) + q * 8);
                    acc[ab][0] = __builtin_amdgcn_mfma_f32_16x16x32_bf16(afr, w0, acc[ab][0], 0, 0, 0);
                    acc[ab][1] = __builtin_amdgcn_mfma_f32_16x16x32_bf16(afr, w1, acc[ab][1], 0, 0, 0);
                }
            }
        int pw0 = half * 8 + q * 2;
#pragma unroll
        for (int nt = 0; nt < 2; ++nt) {
            int oc = nt * 16 + n;
            float p0 = fmaxf(fmaxf(acc[0][nt][0], acc[0][nt][1]),
                             fmaxf(acc[1][nt][0], acc[1][nt][1]));
            float p1 = fmaxf(fmaxf(acc[0][nt][2], acc[0][nt][3]),
                             fmaxf(acc[1][nt][2], acc[1][nt][3]));
            p0 = fmaxf(p0 + bnb2[nt], 0.f) * bns2[nt] + bnm2[nt];
            p1 = fmaxf(p1 + bnb2[nt], 0.f) * bns2[nt] + bnm2[nt];
            s_un[((size_t)(ph + 2) * 20 + (pw0 + 1)) * 32 + oc] = f2bf(p0);
            s_un[((size_t)(ph + 2) * 20 + (pw0 + 2)) * 32 + oc] = f2bf(p1);
        }
    }
    __syncthreads();

    // ---- phase C: conv3 (12 chunks = 6 pool-rows x 2 oc-halves) -----------
    for (int ch = wave; ch < 12; ch += 8) {
        int pr = ch >> 1, nth = ch & 1;
        f32x4 acc[3][2];                       // [conv row r][t2]
#pragma unroll
        for (int r = 0; r < 3; ++r)
#pragma unroll
            for (int t2 = 0; t2 < 2; ++t2) acc[r][t2] = (f32x4){0.f, 0.f, 0.f, 0.f};
#pragma unroll
        for (int ky = 0; ky < 6; ++ky)
#pragma unroll
            for (int kx = 0; kx < 4; ++kx) {
                int kk = ky * 4 + kx;
                short8 w0 = *(const short8*)(wT3 + ((size_t)(kk * 64 + nth * 32 + n) * 32) + q * 8);
                short8 w1 = *(const short8*)(wT3 + ((size_t)(kk * 64 + nth * 32 + 16 + n) * 32) + q * 8);
#pragma unroll
                for (int r = 0; r < 3; ++r) {
                    int row = 3 * pr + r + ky;
                    int col = n + kx;
                    short8 afr = *(const short8*)(s_un + ((size_t)(row * 20 + col) * 32) + q * 8);
                    acc[r][0] = __builtin_amdgcn_mfma_f32_16x16x32_bf16(afr, w0, acc[r][0], 0, 0, 0);
                    acc[r][1] = __builtin_amdgcn_mfma_f32_16x16x32_bf16(afr, w1, acc[r][1], 0, 0, 0);
                }
            }
        size_t ob = (size_t)nl * 1536;
#pragma unroll
        for (int t2 = 0; t2 < 2; ++t2) {
            int oc = nth * 32 + t2 * 16 + n;
            float sc = g3[oc] * rsqrtf(v3[oc] + BN_EPS);
            float mx = -3.4e38f;
#pragma unroll
            for (int r = 0; r < 3; ++r)
#pragma unroll
                for (int e = 0; e < 4; ++e) mx = fmaxf(mx, acc[r][t2][e]);
            float val = fmaxf(mx + c3b[oc], 0.f) * sc + (b3[oc] - m3[oc] * sc);
            out3[ob + (size_t)oc * 24 + pr * 4 + q] = f2bf(val);
        }
    }
}

// ---- fcn: fc1+fc2+fc3+norm fused. 1 block = 16 rows. ----------------------
__global__ __launch_bounds__(256) void fcn_k(
    const unsigned short* __restrict__ A,      // out3b (512,1536) bf16
    const unsigned short* __restrict__ W1, const float* __restrict__ fb1,
    const float* __restrict__ gf1, const float* __restrict__ bf1,
    const float* __restrict__ mf1, const float* __restrict__ vf1,
    const unsigned short* __restrict__ W2, const float* __restrict__ fb2,
    const float* __restrict__ gf2, const float* __restrict__ bf2,
    const float* __restrict__ mf2, const float* __restrict__ vf2,
    const unsigned short* __restrict__ W3, const float* __restrict__ fb3,
    const float* __restrict__ gf3, const float* __restrict__ bf3,
    const float* __restrict__ mf3, const float* __restrict__ vf3,
    float* __restrict__ E, float* __restrict__ sq)
{
    __shared__ __align__(16) unsigned short z1[16 * 512];   // 16 KB
    __shared__ __align__(16) unsigned short z2[16 * 256];   // 8 KB
    __shared__ __align__(16) float z3[16 * 128];            // 8 KB
    const int tid = threadIdx.x;
    const int lane = tid & 63, wave = tid >> 6;
    const int n = lane & 15, q = lane >> 4;
    const int r0 = blockIdx.x * 16;

    // fc1: (16 x 1536) @ (512 x 1536)^T -> z1 bf16
    for (int nt = wave; nt < 32; nt += 4) {
        int col = nt * 16 + n;
        float sc = gf1[col] * rsqrtf(vf1[col] + BN_EPS);
        float bb = fb1[col], mm = bf1[col] - mf1[col] * sc;
        const unsigned short* Ap = A + (size_t)(r0 + n) * 1536 + q * 8;
        const unsigned short* Bp = W1 + (size_t)col * 1536 + q * 8;
        f32x4 acc = (f32x4){0.f, 0.f, 0.f, 0.f};
        for (int kk = 0; kk < 1536; kk += 64) {
            short8 a0 = *(const short8*)(Ap + kk);
            short8 b0 = *(const short8*)(Bp + kk);
            short8 a1 = *(const short8*)(Ap + kk + 32);
            short8 b1 = *(const short8*)(Bp + kk + 32);
            acc = __builtin_amdgcn_mfma_f32_16x16x32_bf16(a0, b0, acc, 0, 0, 0);
            acc = __builtin_amdgcn_mfma_f32_16x16x32_bf16(a1, b1, acc, 0, 0, 0);
        }
#pragma unroll
        for (int e = 0; e < 4; ++e) {
            float val = fmaxf(acc[e] + bb, 0.f) * sc + mm;
            z1[(q * 4 + e) * 512 + col] = f2bf(val);
        }
    }
    __syncthreads();
    // fc2: (16 x 512) @ (256 x 512)^T -> z2 bf16 (A-frags from LDS, b128)
    for (int nt = wave; nt < 16; nt += 4) {
        int col = nt * 16 + n;
        float sc = gf2[col] * rsqrtf(vf2[col] + BN_EPS);
        float bb = fb2[col], mm = bf2[col] - mf2[col] * sc;
        const unsigned short* Bp = W2 + (size_t)col * 512 + q * 8;
        f32x4 acc = (f32x4){0.f, 0.f, 0.f, 0.f};
        for (int kk = 0; kk < 512; kk += 32) {
            short8 a0 = *(const short8*)(z1 + n * 512 + kk + q * 8);
            short8 b0 = *(const short8*)(Bp + kk);
            acc = __builtin_amdgcn_mfma_f32_16x16x32_bf16(a0, b0, acc, 0, 0, 0);
        }
#pragma unroll
        for (int e = 0; e < 4; ++e) {
            float val = fmaxf(acc[e] + bb, 0.f) * sc + mm;
            z2[(q * 4 + e) * 256 + col] = f2bf(val);
        }
    }
    __syncthreads();
    // fc3: (16 x 256) @ (128 x 256)^T -> z3 fp32
    for (int nt = wave; nt < 8; nt += 4) {
        int col = nt * 16 + n;
        float sc = gf3[col] * rsqrtf(vf3[col] + BN_EPS);
        float bb = fb3[col], mm = bf3[col] - mf3[col] * sc;
        const unsigned short* Bp = W3 + (size_t)col * 256 + q * 8;
        f32x4 acc = (f32x4){0.f, 0.f, 0.f, 0.f};
        for (int kk = 0; kk < 256; kk += 32) {
            short8 a0 = *(const short8*)(z2 + n * 256 + kk + q * 8);
            short8 b0 = *(const short8*)(Bp + kk);
            acc = __builtin_amdgcn_mfma_f32_16x16x32_bf16(a0, b0, acc, 0, 0, 0);
        }
#pragma unroll
        for (int e = 0; e < 4; ++e) {
            float val = fmaxf(acc[e] + bb, 0.f) * sc + mm;
            z3[(q * 4 + e) * 128 + col] = val;
        }
    }
    __syncthreads();
    // norm: thread (row_l = tid>>4, j = tid&15) handles 8 cols
    {
        int row_l = tid >> 4, j = tid & 15;
        float4 v0 = *(const float4*)(z3 + row_l * 128 + j * 8);
        float4 v1 = *(const float4*)(z3 + row_l * 128 + j * 8 + 4);
        float s = v0.x * v0.x + v0.y * v0.y + v0.z * v0.z + v0.w * v0.w
                + v1.x * v1.x + v1.y * v1.y + v1.z * v1.z + v1.w * v1.w;
#pragma unroll
        for (int off = 1; off < 16; off <<= 1) s += __shfl_xor(s, off, 16);
        float nn = fmaxf(sqrtf(s), 1e-12f);
        float inv = 1.f / nn;
        int row = r0 + row_l;
        float4 e0, e1;
        e0.x = v0.x * inv; e0.y = v0.y * inv; e0.z = v0.z * inv; e0.w = v0.w * inv;
        e1.x = v1.x * inv; e1.y = v1.y * inv; e1.z = v1.z * inv; e1.w = v1.w * inv;
        *(float4*)(E + (size_t)row * 128 + j * 8) = e0;
        *(float4*)(E + (size_t)row * 128 + j * 8 + 4) = e1;
        if (j == 0) sq[row] = s * inv * inv;
    }
}

// ---- pairwise distance + global max ---------------------------------------
__global__ __launch_bounds__(256) void dist_k(const float* __restrict__ E,
                                              const float* __restrict__ sq,
                                              float* __restrict__ D,
                                              unsigned* __restrict__ mxslot)
{
    __shared__ __align__(16) float Ei[16 * 132];
    __shared__ __align__(16) float Ej[16 * 132];
    __shared__ float red[256];
    const int tid = threadIdx.x;
    const int bi = blockIdx.y * 16, bj = blockIdx.x * 16;
    {
        int lr = tid >> 4, lc = (tid & 15) * 8;
        float4 a0 = *(const float4*)(E + (bi + lr) * 128 + lc);
        float4 a1 = *(const float4*)(E + (bi + lr) * 128 + lc + 4);
        *(float4*)(Ei + lr * 132 + lc) = a0;
        *(float4*)(Ei + lr * 132 + lc + 4) = a1;
        float4 b0 = *(const float4*)(E + (bj + lr) * 128 + lc);
        float4 b1 = *(const float4*)(E + (bj + lr) * 128 + lc + 4);
        *(float4*)(Ej + lr * 132 + lc) = b0;
        *(float4*)(Ej + lr * 132 + lc + 4) = b1;
    }
    __syncthreads();
    const int tx = tid & 15, ty = tid >> 4;
    float dot = 0.f;
#pragma unroll 4
    for (int k = 0; k < 128; k += 4) {
        float4 a = *(const float4*)(Ei + ty * 132 + k);
        float4 b = *(const float4*)(Ej + tx * 132 + k);
        dot = fmaf(a.x, b.x, dot); dot = fmaf(a.y, b.y, dot);
        dot = fmaf(a.z, b.z, dot); dot = fmaf(a.w, b.w, dot);
    }
    int i = bi + ty, j = bj + tx;
    float d2 = sq[i] + sq[j] - 2.f * dot;
    float dist = sqrtf(fmaxf(d2, 1e-12f));
    dist = (d2 > 0.f) ? dist : 0.f;
    if (i == j) dist = 0.f;
    D[i * 512 + j] = dist;
    red[tid] = dist;
    __syncthreads();
    for (int s2 = 128; s2 > 0; s2 >>= 1) {
        if (tid < s2) red[tid] = fmaxf(red[tid], red[tid + s2]);
        __syncthreads();
    }
    if (tid == 0) atomicMax(mxslot, __float_as_uint(red[0]));
}

__global__ __launch_bounds__(256) void scale_k(float* __restrict__ D,
                                               const unsigned* __restrict__ mxslot)
{
    int idx = blockIdx.x * 256 + threadIdx.x;
    float M = __uint_as_float(*mxslot);
    D[idx] = D[idx] / M;
}

// ---------------------------------------------------------------------------
extern "C" void kernel_launch(void* const* d_in, const int* in_sizes, int n_in,
                              void* d_out, int out_size, void* d_ws, size_t ws_size,
                              hipStream_t stream)
{
    (void)in_sizes; (void)n_in; (void)out_size; (void)ws_size;
    const float* x    = (const float*)d_in[0];
    const float* c1w  = (const float*)d_in[1];
    const float* c1b  = (const float*)d_in[2];
    const float* g1   = (const float*)d_in[3];
    const float* b1   = (const float*)d_in[4];
    const float* m1   = (const float*)d_in[5];
    const float* v1   = (const float*)d_in[6];
    const float* c2w  = (const float*)d_in[7];
    const float* c2b  = (const float*)d_in[8];
    const float* g2   = (const float*)d_in[9];
    const float* b2   = (const float*)d_in[10];
    const float* m2   = (const float*)d_in[11];
    const float* v2   = (const float*)d_in[12];
    const float* c3w  = (const float*)d_in[13];
    const float* c3b  = (const float*)d_in[14];
    const float* g3   = (const float*)d_in[15];
    const float* b3   = (const float*)d_in[16];
    const float* m3   = (const float*)d_in[17];
    const float* v3   = (const float*)d_in[18];
    const float* fw1  = (const float*)d_in[19];
    const float* fb1  = (const float*)d_in[20];
    const float* gf1  = (const float*)d_in[21];
    const float* bf1  = (const float*)d_in[22];
    const float* mf1  = (const float*)d_in[23];
    const float* vf1  = (const float*)d_in[24];
    const float* fw2  = (const float*)d_in[25];
    const float* fb2  = (const float*)d_in[26];
    const float* gf2  = (const float*)d_in[27];
    const float* bf2  = (const float*)d_in[28];
    const float* mf2  = (const float*)d_in[29];
    const float* vf2  = (const float*)d_in[30];
    const float* fw3  = (const float*)d_in[31];
    const float* fb3  = (const float*)d_in[32];
    const float* gf3  = (const float*)d_in[33];
    const float* bf3  = (const float*)d_in[34];
    const float* mf3  = (const float*)d_in[35];
    const float* vf3  = (const float*)d_in[36];

    float* ws = (float*)d_ws;
    // ---- ws layout (float offsets, 16B-aligned), total ~3.9 MB ------------
    float* E    = ws + 0;                                    // 65536
    float* sq   = ws + 65536;                                // 512
    unsigned* mx = (unsigned*)(ws + 66048);
    unsigned short* wT1b = (unsigned short*)(ws + 66064);    // 512 ush
    unsigned short* wT2b = (unsigned short*)(ws + 66320);    // 12288 ush
    unsigned short* wT3b = (unsigned short*)(ws + 72464);    // 49152 ush
    unsigned short* fw1b = (unsigned short*)(ws + 97040);    // 786432 ush
    unsigned short* fw2b = (unsigned short*)(ws + 490256);   // 131072 ush
    unsigned short* fw3b = (unsigned short*)(ws + 555792);   // 32768 ush
    unsigned short* out3b= (unsigned short*)(ws + 572176);   // 786432 ush

    float* out = (float*)d_out;

    repack_k<<<3072, 256, 0, stream>>>(c1w, c2w, c3w, fw1, fw2, fw3,
                                       wT1b, wT2b, wT3b, fw1b, fw2b, fw3b, mx);
    conv_all<<<512, 512, 0, stream>>>(x, wT1b, wT2b, wT3b,
                                      c1b, g1, b1, m1, v1,
                                      c2b, g2, b2, m2, v2,
                                      c3b, g3, b3, m3, v3, out3b);
    fcn_k<<<32, 256, 0, stream>>>(out3b,
                                  fw1b, fb1, gf1, bf1, mf1, vf1,
                                  fw2b, fb2, gf2, bf2, mf2, vf2,
                                  fw3b, fb3, gf3, bf3, mf3, vf3,
                                  E, sq);
    dist_k<<<dim3(32, 32), 256, 0, stream>>>(E, sq, out, mx);
    scale_k<<<1024, 256, 0, stream>>>(out, mx);
}

// Round 9
// 219.560 us; speedup vs baseline: 1.2637x; 1.2637x over previous
//
#include <hip/hip_runtime.h>
#include <math.h>

// ---------------------------------------------------------------------------
// Round 9: R8 post-mortem showed fcn_k (32 blocks, row-fused FC) is latency-
// bound at 85us / 1.3% occupancy. Revert FC stack to R7's proven wide-grid
// LDS-free fc_m (256/128/64 blocks) + norm_k. KEEP conv_all fusion (saved
// ~25-30us) and repack-with-mx-zero. 8 dispatches.
// ---------------------------------------------------------------------------

#define BN_EPS 1e-5f

typedef __attribute__((ext_vector_type(8))) short short8;   // 8 bf16 = 4 VGPR
typedef __attribute__((ext_vector_type(4))) float f32x4;

__device__ __forceinline__ unsigned short f2bf(float f) {
    unsigned u = __float_as_uint(f);
    u += 0x7fffu + ((u >> 16) & 1u);          // round-to-nearest-even
    return (unsigned short)(u >> 16);
}

// ---- weight repack + fc-weight bf16 cast + mx zero -------------------------
__global__ __launch_bounds__(256) void repack_k(
    const float* __restrict__ w1, const float* __restrict__ w2,
    const float* __restrict__ w3,
    const float* __restrict__ fw1, const float* __restrict__ fw2,
    const float* __restrict__ fw3,
    unsigned short* __restrict__ wT1b,
    unsigned short* __restrict__ wT2b, unsigned short* __restrict__ wT3b,
    unsigned short* __restrict__ fw1b, unsigned short* __restrict__ fw2b,
    unsigned short* __restrict__ fw3b, unsigned* __restrict__ mxslot)
{
    int t = blockIdx.x * 256 + threadIdx.x;
    if (t == 0) *mxslot = 0u;
    if (t < 512) {
        int k = t & 31, oc = t >> 5;
        wT1b[t] = (k < 24) ? f2bf(w1[oc * 24 + k]) : (unsigned short)0;
    }
    if (t < 12288) {
        int k = t & 31, oc = (t >> 5) & 31, kk = t >> 10;
        int ky = kk >> 1, kxp = kk & 1;
        int hi = k >> 4, ic = k & 15;
        int kx = 2 * kxp + hi;
        wT2b[t] = f2bf(w2[((oc * 16 + ic) * 6 + ky) * 4 + kx]);
    }
    if (t < 49152) {
        int ic = t & 31, oc = (t >> 5) & 63, kk = t >> 11;
        int ky = kk >> 2, kx = kk & 3;
        wT3b[t] = f2bf(w3[((oc * 32 + ic) * 6 + ky) * 4 + kx]);
    }
    if (t < 786432) fw1b[t] = f2bf(fw1[t]);
    if (t < 131072) fw2b[t] = f2bf(fw2[t]);
    if (t < 32768)  fw3b[t] = f2bf(fw3[t]);
}

// ---- conv_all: full conv stack, 1 block = 1 batch (proven R8) --------------
__global__ __launch_bounds__(512) void conv_all(
    const float* __restrict__ x, const unsigned short* __restrict__ wT1,
    const unsigned short* __restrict__ wT2, const unsigned short* __restrict__ wT3,
    const float* __restrict__ c1b, const float* __restrict__ g1,
    const float* __restrict__ b1, const float* __restrict__ m1,
    const float* __restrict__ v1,
    const float* __restrict__ c2b, const float* __restrict__ g2,
    const float* __restrict__ b2, const float* __restrict__ m2,
    const float* __restrict__ v2,
    const float* __restrict__ c3b, const float* __restrict__ g3,
    const float* __restrict__ b3, const float* __restrict__ m3,
    const float* __restrict__ v3,
    unsigned short* __restrict__ out3)
{
    __shared__ __align__(16) unsigned short s_out1[41 * 36 * 16];  // 47232 B
    __shared__ __align__(16) unsigned short s_un[24 * 20 * 32];    // 30720 B
    const int tid = threadIdx.x, nl = blockIdx.x;
    const int lane = tid & 63, wave = tid >> 6;
    const int n = lane & 15, q = lane >> 4;
    unsigned short* pa = s_un;           // [79][68]: pa[r][c] = img[r-2][c-1]
    unsigned short* pb = s_un + 5372;    // [79][68]: pb[r][c] = img[r-2][c-2]

    {
        unsigned* z32 = (unsigned*)s_un;
        for (int i = tid; i < 5372; i += 512) z32[i] = 0u;
        uint4 z4; z4.x = z4.y = z4.z = z4.w = 0u;
        for (int pc = tid; pc < 324; pc += 512) {
            int row, colc;
            if (pc < 180) { row = pc / 36; colc = pc % 36; if (row >= 2) row += 36; }
            else { int pz = pc - 180; row = 2 + (pz >> 2); colc = (pz & 3) ? 32 + (pz & 3) : 0; }
            uint4* d = (uint4*)(s_out1 + ((size_t)row * 36 + colc) * 16);
            d[0] = z4; d[1] = z4;
        }
    }
    __syncthreads();
    {
        const float4* src = (const float4*)(x + (size_t)nl * 4608);
        for (int i = tid; i < 1152; i += 512) {
            float4 val = src[i];
            int f = i * 4, row = (f >> 6) + 2, c = (f & 63) + 1;   // c odd
            unsigned short h0 = f2bf(val.x), h1 = f2bf(val.y);
            unsigned short h2 = f2bf(val.z), h3 = f2bf(val.w);
            unsigned short* ap = pa + row * 68 + c;
            ap[0] = h0; ap[1] = h1; ap[2] = h2; ap[3] = h3;
            unsigned* bp = (unsigned*)(pb + row * 68 + c + 1);     // even idx
            bp[0] = (unsigned)h0 | ((unsigned)h1 << 16);
            bp[1] = (unsigned)h2 | ((unsigned)h3 << 16);
        }
    }
    const float sc1 = g1[n] * rsqrtf(v1[n] + BN_EPS);
    const float bb1 = c1b[n];
    const float mm1 = b1[n] - m1[n] * sc1;
    const short8 bfr1 = *(const short8*)(wT1 + n * 32 + q * 8);
    __syncthreads();

    // phase A: conv1
    for (int i = 0; i < 36; ++i) {
        int t = wave * 36 + i;
        int pooled = 4 * t + (n >> 2);
        int ph = pooled >> 5, pw = pooled & 31;
        int py = (n >> 1) & 1, px = n & 1;
        int oh = 2 * ph + py, ow = 2 * pw + px;
        int r0 = (oh + 2 * q) * 68;
        const unsigned* base = px ? (const unsigned*)(pb + r0 + ow + 1)
                                  : (const unsigned*)(pa + r0 + ow);
        uint4 uu;
        uu.x = base[0];  uu.y = base[1];
        uu.z = base[34]; uu.w = base[35];
        short8 afr = *reinterpret_cast<short8*>(&uu);
        f32x4 acc = (f32x4){0.f, 0.f, 0.f, 0.f};
        acc = __builtin_amdgcn_mfma_f32_16x16x32_bf16(afr, bfr1, acc, 0, 0, 0);
        int po = 4 * t + q, oph = po >> 5, opw = po & 31;
        float mx = fmaxf(fmaxf(acc[0], acc[1]), fmaxf(acc[2], acc[3]));
        float val = fmaxf(mx + bb1, 0.f) * sc1 + mm1;
        s_out1[((oph + 2) * 36 + (opw + 1)) * 16 + n] = f2bf(val);
    }
    __syncthreads();
    {
        uint4 z4; z4.x = z4.y = z4.z = z4.w = 0u;
        for (int pc = tid; pc < 192; pc += 512) {
            int row, colc;
            if (pc < 120) { row = pc / 20; colc = pc % 20; if (row >= 2) row += 18; }
            else { int pz = pc - 120; row = 2 + (pz >> 2); colc = (pz & 3) ? 16 + (pz & 3) : 0; }
            uint4* d = (uint4*)(s_un + ((size_t)row * 20 + colc) * 32);
            d[0] = z4; d[1] = z4; d[2] = z4; d[3] = z4;
        }
    }
    float bnb2[2], bns2[2], bnm2[2];
#pragma unroll
    for (int nt = 0; nt < 2; ++nt) {
        int oc = nt * 16 + n;
        float sc = g2[oc] * rsqrtf(v2[oc] + BN_EPS);
        bnb2[nt] = c2b[oc]; bns2[nt] = sc; bnm2[nt] = b2[oc] - m2[oc] * sc;
    }
    __syncthreads();

    // phase B: conv2
    for (int pp = wave; pp < 36; pp += 8) {
        int ph = pp >> 1, half = pp & 1;
        f32x4 acc[2][2];
#pragma unroll
        for (int ab = 0; ab < 2; ++ab)
#pragma unroll
            for (int nt = 0; nt < 2; ++nt) acc[ab][nt] = (f32x4){0.f, 0.f, 0.f, 0.f};
#pragma unroll
        for (int ky = 0; ky < 6; ++ky)
#pragma unroll
            for (int kxp = 0; kxp < 2; ++kxp) {
                int kk = ky * 2 + kxp;
                short8 w0 = *(const short8*)(wT2 + ((size_t)(kk * 32 + n) * 32) + q * 8);
                short8 w1 = *(const short8*)(wT2 + ((size_t)(kk * 32 + 16 + n) * 32) + q * 8);
                int col = half * 16 + n + 2 * kxp;
#pragma unroll
                for (int ab = 0; ab < 2; ++ab) {
                    int row = 2 * ph + ab + ky;
                    short8 afr = *(const short8*)(s_out1 + ((size_t)(row * 36 + col) * 16) + q * 8);
                    acc[ab][0] = __builtin_amdgcn_mfma_f32_16x16x32_bf16(afr, w0, acc[ab][0], 0, 0, 0);
                    acc[ab][1] = __builtin_amdgcn_mfma_f32_16x16x32_bf16(afr, w1, acc[ab][1], 0, 0, 0);
                }
            }
        int pw0 = half * 8 + q * 2;
#pragma unroll
        for (int nt = 0; nt < 2; ++nt) {
            int oc = nt * 16 + n;
            float p0 = fmaxf(fmaxf(acc[0][nt][0], acc[0][nt][1]),
                             fmaxf(acc[1][nt][0], acc[1][nt][1]));
            float p1 = fmaxf(fmaxf(acc[0][nt][2], acc[0][nt][3]),
                             fmaxf(acc[1][nt][2], acc[1][nt][3]));
            p0 = fmaxf(p0 + bnb2[nt], 0.f) * bns2[nt] + bnm2[nt];
            p1 = fmaxf(p1 + bnb2[nt], 0.f) * bns2[nt] + bnm2[nt];
            s_un[((size_t)(ph + 2) * 20 + (pw0 + 1)) * 32 + oc] = f2bf(p0);
            s_un[((size_t)(ph + 2) * 20 + (pw0 + 2)) * 32 + oc] = f2bf(p1);
        }
    }
    __syncthreads();

    // phase C: conv3
    for (int ch = wave; ch < 12; ch += 8) {
        int pr = ch >> 1, nth = ch & 1;
        f32x4 acc[3][2];
#pragma unroll
        for (int r = 0; r < 3; ++r)
#pragma unroll
            for (int t2 = 0; t2 < 2; ++t2) acc[r][t2] = (f32x4){0.f, 0.f, 0.f, 0.f};
#pragma unroll
        for (int ky = 0; ky < 6; ++ky)
#pragma unroll
            for (int kx = 0; kx < 4; ++kx) {
                int kk = ky * 4 + kx;
                short8 w0 = *(const short8*)(wT3 + ((size_t)(kk * 64 + nth * 32 + n) * 32) + q * 8);
                short8 w1 = *(const short8*)(wT3 + ((size_t)(kk * 64 + nth * 32 + 16 + n) * 32) + q * 8);
#pragma unroll
                for (int r = 0; r < 3; ++r) {
                    int row = 3 * pr + r + ky;
                    int col = n + kx;
                    short8 afr = *(const short8*)(s_un + ((size_t)(row * 20 + col) * 32) + q * 8);
                    acc[r][0] = __builtin_amdgcn_mfma_f32_16x16x32_bf16(afr, w0, acc[r][0], 0, 0, 0);
                    acc[r][1] = __builtin_amdgcn_mfma_f32_16x16x32_bf16(afr, w1, acc[r][1], 0, 0, 0);
                }
            }
        size_t ob = (size_t)nl * 1536;
#pragma unroll
        for (int t2 = 0; t2 < 2; ++t2) {
            int oc = nth * 32 + t2 * 16 + n;
            float sc = g3[oc] * rsqrtf(v3[oc] + BN_EPS);
            float mx = -3.4e38f;
#pragma unroll
            for (int r = 0; r < 3; ++r)
#pragma unroll
                for (int e = 0; e < 4; ++e) mx = fmaxf(mx, acc[r][t2][e]);
            float val = fmaxf(mx + c3b[oc], 0.f) * sc + (b3[oc] - m3[oc] * sc);
            out3[ob + (size_t)oc * 24 + pr * 4 + q] = f2bf(val);
        }
    }
}

// ---- fc (MFMA, LDS-free, wide grid — proven R7) ---------------------------
__global__ __launch_bounds__(256) void fc_m(
    const unsigned short* __restrict__ A, const unsigned short* __restrict__ W,
    const float* __restrict__ bias, const float* __restrict__ g,
    const float* __restrict__ bt, const float* __restrict__ m,
    const float* __restrict__ v, unsigned short* __restrict__ out_b,
    float* __restrict__ out_f, int K, int N, int mode)   // mode 0=bf16, 1=f32
{
    const int tid = threadIdx.x;
    const int lane = tid & 63, wave = tid >> 6;
    const int n = lane & 15, q = lane >> 4;
    const int wr = wave >> 1, wc = wave & 1;
    const int r0 = blockIdx.y * 32 + wr * 16;
    const int c0 = blockIdx.x * 32 + wc * 16;
    const int col = c0 + n;

    float sc = g[col] * rsqrtf(v[col] + BN_EPS);
    float bb = bias[col];
    float mm = bt[col] - m[col] * sc;

    const unsigned short* Ap = A + (size_t)(r0 + n) * K + q * 8;
    const unsigned short* Bp = W + (size_t)col * K + q * 8;

    f32x4 acc = (f32x4){0.f, 0.f, 0.f, 0.f};
    for (int kk = 0; kk < K; kk += 64) {
        short8 a0 = *(const short8*)(Ap + kk);
        short8 b0 = *(const short8*)(Bp + kk);
        short8 a1 = *(const short8*)(Ap + kk + 32);
        short8 b1 = *(const short8*)(Bp + kk + 32);
        acc = __builtin_amdgcn_mfma_f32_16x16x32_bf16(a0, b0, acc, 0, 0, 0);
        acc = __builtin_amdgcn_mfma_f32_16x16x32_bf16(a1, b1, acc, 0, 0, 0);
    }
#pragma unroll
    for (int e = 0; e < 4; ++e) {
        int row = r0 + q * 4 + e;
        float val = fmaxf(acc[e] + bb, 0.f) * sc + mm;
        if (mode == 0) out_b[(size_t)row * N + col] = f2bf(val);
        else           out_f[(size_t)row * N + col] = val;
    }
}

// ---- row L2-normalize; emit sq = sum(e^2) ---------------------------------
__global__ __launch_bounds__(128) void norm_k(const float* __restrict__ f3,
                                              float* __restrict__ E,
                                              float* __restrict__ sq)
{
    __shared__ float red[2];
    const int row = blockIdx.x, tid = threadIdx.x;
    float vv = f3[row * 128 + tid];
    float s = vv * vv;
#pragma unroll
    for (int off = 32; off >= 1; off >>= 1) s += __shfl_down(s, off, 64);
    if ((tid & 63) == 0) red[tid >> 6] = s;
    __syncthreads();
    float total = red[0] + red[1];
    float nn = fmaxf(sqrtf(total), 1e-12f);
    E[row * 128 + tid] = vv / nn;
    if (tid == 0) sq[row] = total / (nn * nn);
}

// ---- pairwise distance + global max ---------------------------------------
__global__ __launch_bounds__(256) void dist_k(const float* __restrict__ E,
                                              const float* __restrict__ sq,
                                              float* __restrict__ D,
                                              unsigned* __restrict__ mxslot)
{
    __shared__ __align__(16) float Ei[16 * 132];
    __shared__ __align__(16) float Ej[16 * 132];
    __shared__ float red[256];
    const int tid = threadIdx.x;
    const int bi = blockIdx.y * 16, bj = blockIdx.x * 16;
    {
        int lr = tid >> 4, lc = (tid & 15) * 8;
        float4 a0 = *(const float4*)(E + (bi + lr) * 128 + lc);
        float4 a1 = *(const float4*)(E + (bi + lr) * 128 + lc + 4);
        *(float4*)(Ei + lr * 132 + lc) = a0;
        *(float4*)(Ei + lr * 132 + lc + 4) = a1;
        float4 b0 = *(const float4*)(E + (bj + lr) * 128 + lc);
        float4 b1 = *(const float4*)(E + (bj + lr) * 128 + lc + 4);
        *(float4*)(Ej + lr * 132 + lc) = b0;
        *(float4*)(Ej + lr * 132 + lc + 4) = b1;
    }
    __syncthreads();
    const int tx = tid & 15, ty = tid >> 4;
    float dot = 0.f;
#pragma unroll 4
    for (int k = 0; k < 128; k += 4) {
        float4 a = *(const float4*)(Ei + ty * 132 + k);
        float4 b = *(const float4*)(Ej + tx * 132 + k);
        dot = fmaf(a.x, b.x, dot); dot = fmaf(a.y, b.y, dot);
        dot = fmaf(a.z, b.z, dot); dot = fmaf(a.w, b.w, dot);
    }
    int i = bi + ty, j = bj + tx;
    float d2 = sq[i] + sq[j] - 2.f * dot;
    float dist = sqrtf(fmaxf(d2, 1e-12f));
    dist = (d2 > 0.f) ? dist : 0.f;
    if (i == j) dist = 0.f;
    D[i * 512 + j] = dist;
    red[tid] = dist;
    __syncthreads();
    for (int s2 = 128; s2 > 0; s2 >>= 1) {
        if (tid < s2) red[tid] = fmaxf(red[tid], red[tid + s2]);
        __syncthreads();
    }
    if (tid == 0) atomicMax(mxslot, __float_as_uint(red[0]));
}

__global__ __launch_bounds__(256) void scale_k(float* __restrict__ D,
                                               const unsigned* __restrict__ mxslot)
{
    int idx = blockIdx.x * 256 + threadIdx.x;
    float M = __uint_as_float(*mxslot);
    D[idx] = D[idx] / M;
}

// ---------------------------------------------------------------------------
extern "C" void kernel_launch(void* const* d_in, const int* in_sizes, int n_in,
                              void* d_out, int out_size, void* d_ws, size_t ws_size,
                              hipStream_t stream)
{
    (void)in_sizes; (void)n_in; (void)out_size; (void)ws_size;
    const float* x    = (const float*)d_in[0];
    const float* c1w  = (const float*)d_in[1];
    const float* c1b  = (const float*)d_in[2];
    const float* g1   = (const float*)d_in[3];
    const float* b1   = (const float*)d_in[4];
    const float* m1   = (const float*)d_in[5];
    const float* v1   = (const float*)d_in[6];
    const float* c2w  = (const float*)d_in[7];
    const float* c2b  = (const float*)d_in[8];
    const float* g2   = (const float*)d_in[9];
    const float* b2   = (const float*)d_in[10];
    const float* m2   = (const float*)d_in[11];
    const float* v2   = (const float*)d_in[12];
    const float* c3w  = (const float*)d_in[13];
    const float* c3b  = (const float*)d_in[14];
    const float* g3   = (const float*)d_in[15];
    const float* b3   = (const float*)d_in[16];
    const float* m3   = (const float*)d_in[17];
    const float* v3   = (const float*)d_in[18];
    const float* fw1  = (const float*)d_in[19];
    const float* fb1  = (const float*)d_in[20];
    const float* gf1  = (const float*)d_in[21];
    const float* bf1  = (const float*)d_in[22];
    const float* mf1  = (const float*)d_in[23];
    const float* vf1  = (const float*)d_in[24];
    const float* fw2  = (const float*)d_in[25];
    const float* fb2  = (const float*)d_in[26];
    const float* gf2  = (const float*)d_in[27];
    const float* bf2  = (const float*)d_in[28];
    const float* mf2  = (const float*)d_in[29];
    const float* vf2  = (const float*)d_in[30];
    const float* fw3  = (const float*)d_in[31];
    const float* fb3  = (const float*)d_in[32];
    const float* gf3  = (const float*)d_in[33];
    const float* bf3  = (const float*)d_in[34];
    const float* mf3  = (const float*)d_in[35];
    const float* vf3  = (const float*)d_in[36];

    float* ws = (float*)d_ws;
    // ---- ws layout (float offsets, 16B-aligned), total ~4.6 MB ------------
    float* E    = ws + 0;                                    // 65536
    float* sq   = ws + 65536;                                // 512
    float* f3v  = ws + 66048;                                // 65536
    unsigned* mx = (unsigned*)(ws + 131584);
    unsigned short* wT1b = (unsigned short*)(ws + 131600);   // 512 ush
    unsigned short* wT2b = (unsigned short*)(ws + 131856);   // 12288 ush
    unsigned short* wT3b = (unsigned short*)(ws + 138000);   // 49152 ush
    unsigned short* fw1b = (unsigned short*)(ws + 162576);   // 786432 ush
    unsigned short* fw2b = (unsigned short*)(ws + 555792);   // 131072 ush
    unsigned short* fw3b = (unsigned short*)(ws + 621328);   // 32768 ush
    unsigned short* out3b= (unsigned short*)(ws + 637712);   // 786432 ush
    unsigned short* a1b  = (unsigned short*)(ws + 1030928);  // 262144 ush
    unsigned short* a2b  = (unsigned short*)(ws + 1162000);  // 131072 ush

    float* out = (float*)d_out;

    repack_k<<<3072, 256, 0, stream>>>(c1w, c2w, c3w, fw1, fw2, fw3,
                                       wT1b, wT2b, wT3b, fw1b, fw2b, fw3b, mx);
    conv_all<<<512, 512, 0, stream>>>(x, wT1b, wT2b, wT3b,
                                      c1b, g1, b1, m1, v1,
                                      c2b, g2, b2, m2, v2,
                                      c3b, g3, b3, m3, v3, out3b);
    fc_m<<<dim3(16, 16), 256, 0, stream>>>(out3b, fw1b, fb1, gf1, bf1, mf1, vf1,
                                           a1b, nullptr, 1536, 512, 0);
    fc_m<<<dim3(8, 16), 256, 0, stream>>>(a1b, fw2b, fb2, gf2, bf2, mf2, vf2,
                                          a2b, nullptr, 512, 256, 0);
    fc_m<<<dim3(4, 16), 256, 0, stream>>>(a2b, fw3b, fb3, gf3, bf3, mf3, vf3,
                                          nullptr, f3v, 256, 128, 1);
    norm_k<<<512, 128, 0, stream>>>(f3v, E, sq);
    dist_k<<<dim3(32, 32), 256, 0, stream>>>(E, sq, out, mx);
    scale_k<<<1024, 256, 0, stream>>>(out, mx);
}